// Round 1
// baseline (811.028 us; speedup 1.0000x reference)
//
#include <hip/hip_runtime.h>

#define IN_F 1024
#define ASS 100000
#define OUT_F 1024
#define TOTAL (IN_F + ASS + OUT_F)
#define ASS0 IN_F
#define OUT0 (IN_F + ASS)
#define NUM_ROUNDS 24

// ---------------------------------------------------------------------------
// Workspace layout (all zero-initialized by k_init each call):
//   mem   : TOTAL f32   -- neuron memory
//   delta : TOTAL f32   -- per-round incoming sum (scatter target)
//   status: TOTAL i32   -- 0=inactive, 1=working, 2=activated
//   got   : TOTAL i32   -- "received a message this round" flag
// ---------------------------------------------------------------------------

__global__ __launch_bounds__(256) void k_init(float* mem, float* delta,
                                              int* status, int* got) {
    int i = blockIdx.x * 256 + threadIdx.x;
    if (i < TOTAL) {
        mem[i] = 0.f;
        delta[i] = 0.f;
        status[i] = 0;
        got[i] = 0;
    }
}

// Input phase: each input edge sends x[src]*w into mem[dst]; mark receivers.
__global__ __launch_bounds__(256) void k_input(const float* __restrict__ x,
                                               const float* __restrict__ w,
                                               const int* __restrict__ src,
                                               const int* __restrict__ dst,
                                               int n, float* mem, int* got) {
    for (int e = blockIdx.x * 256 + threadIdx.x; e < n; e += gridDim.x * 256) {
        int s = src[e];
        int d = dst[e];
        atomicAdd(&mem[d], x[s] * w[e]);
        got[d] = 1;  // benign race: all writers store 1
    }
}

// status = recv ? 1 : 0 ; clear got for round use.
__global__ __launch_bounds__(256) void k_status0(int* status, int* got) {
    int i = blockIdx.x * 256 + threadIdx.x;
    if (i < TOTAL) {
        status[i] = got[i] ? 1 : 0;
        got[i] = 0;
    }
}

// One propagation round, edge pass: working sources fire tanh(mem)*w -> delta.
// Reads mem/status from BEFORE this round's update (k_update runs after).
__global__ __launch_bounds__(256) void k_edge(const float* __restrict__ w,
                                              const int* __restrict__ src,
                                              const int* __restrict__ dst,
                                              int n,
                                              const float* __restrict__ mem,
                                              const int* __restrict__ status,
                                              float* delta, int* got) {
    for (int e = blockIdx.x * 256 + threadIdx.x; e < n; e += gridDim.x * 256) {
        int s = src[e];
        if (status[s] == 1) {  // all assoc-edge sources are assoc neurons
            float v = tanhf(mem[s]) * w[e];
            int d = dst[e];
            atomicAdd(&delta[d], v);
            got[d] = 1;
        }
    }
}

// Node update: fired -> mem=delta,status=2; else mem+=delta, fresh receivers
// become working. Clears delta/got for the next round.
__global__ __launch_bounds__(256) void k_update(float* mem, float* delta,
                                                int* status, int* got) {
    int i = blockIdx.x * 256 + threadIdx.x;
    if (i < TOTAL) {
        int st = status[i];
        bool fire = (st == 1) && (i >= ASS0) && (i < OUT0);
        float d = delta[i];
        mem[i] = fire ? d : (mem[i] + d);
        status[i] = fire ? 2 : ((got[i] && st == 0) ? 1 : st);
        delta[i] = 0.f;
        got[i] = 0;
    }
}

__global__ __launch_bounds__(256) void k_out(const float* __restrict__ mem,
                                             float* __restrict__ out) {
    int i = blockIdx.x * 256 + threadIdx.x;
    if (i < OUT_F) out[i] = tanhf(mem[OUT0 + i]);
}

extern "C" void kernel_launch(void* const* d_in, const int* in_sizes, int n_in,
                              void* d_out, int out_size, void* d_ws, size_t ws_size,
                              hipStream_t stream) {
    // setup_inputs() order:
    //   0: x (1,1024) f32         1: input_weights (E_in) f32
    //   2: assoc_weights (E_a) f32
    //   3: in_edge_src (E_in) i32 4: in_edge_dst (E_in) i32
    //   5: ass_edge_src (E_a) i32 6: ass_edge_dst (E_a) i32
    const float* x   = (const float*)d_in[0];
    const float* iw  = (const float*)d_in[1];
    const float* aw  = (const float*)d_in[2];
    const int*   ies = (const int*)d_in[3];
    const int*   ied = (const int*)d_in[4];
    const int*   aes = (const int*)d_in[5];
    const int*   aed = (const int*)d_in[6];
    const int E_in = in_sizes[1];
    const int E_a  = in_sizes[2];
    float* out = (float*)d_out;

    char* ws = (char*)d_ws;
    float* mem   = (float*)ws;
    float* delta = mem + TOTAL;
    int* status  = (int*)(delta + TOTAL);
    int* got     = status + TOTAL;

    const int nodeBlocks = (TOTAL + 255) / 256;

    k_init<<<nodeBlocks, 256, 0, stream>>>(mem, delta, status, got);

    int inBlocks = (E_in + 255) / 256;
    if (inBlocks > 1024) inBlocks = 1024;
    k_input<<<inBlocks, 256, 0, stream>>>(x, iw, ies, ied, E_in, mem, got);
    k_status0<<<nodeBlocks, 256, 0, stream>>>(status, got);

    int eBlocks = (E_a + 255) / 256;
    if (eBlocks > 2048) eBlocks = 2048;
    for (int r = 0; r < NUM_ROUNDS; ++r) {
        k_edge<<<eBlocks, 256, 0, stream>>>(aw, aes, aed, E_a, mem, status,
                                            delta, got);
        k_update<<<nodeBlocks, 256, 0, stream>>>(mem, delta, status, got);
    }

    k_out<<<(OUT_F + 255) / 256, 256, 0, stream>>>(mem, out);
}